// Round 1
// baseline (633.538 us; speedup 1.0000x reference)
//
#include <hip/hip_runtime.h>

#define LL   2048
#define BB   4
#define DD   512
#define HH   8
#define DKK  64
#define WBAND 12
#define NBAND 25   // 2*WBAND+1

// ---------------------------------------------------------------------------
// proj: Out[b,h,l,dk] = sum_d X[(l*B+b), d] * Wm[(h*64+dk), d] + bias
// NT GEMM, M=L*B=8192, N=512, K=512. 64x64 tile, 4x4 micro, fp32.
// ---------------------------------------------------------------------------
__global__ __launch_bounds__(256) void proj_kernel(
    const float* __restrict__ X, const float* __restrict__ Wm,
    const float* __restrict__ bias, float* __restrict__ Out)
{
    __shared__ float At[64][68];
    __shared__ float Bt[64][68];
    const int t  = threadIdx.x;
    const int ti = t >> 4;
    const int tj = t & 15;
    const int mbase = blockIdx.x * 64;
    const int nbase = blockIdx.y * 64;
    float acc[4][4] = {};

    for (int k0 = 0; k0 < DD; k0 += 64) {
        __syncthreads();
#pragma unroll
        for (int i = 0; i < 4; ++i) {
            int flat = t + i * 256;          // float4 index, 1024 total
            int r = flat >> 4;
            int c = (flat & 15) << 2;
            *reinterpret_cast<float4*>(&At[r][c]) =
                *reinterpret_cast<const float4*>(&X[(size_t)(mbase + r) * DD + k0 + c]);
            *reinterpret_cast<float4*>(&Bt[r][c]) =
                *reinterpret_cast<const float4*>(&Wm[(size_t)(nbase + r) * DD + k0 + c]);
        }
        __syncthreads();
#pragma unroll
        for (int d = 0; d < 64; d += 4) {
            float4 a4[4], b4[4];
#pragma unroll
            for (int i = 0; i < 4; ++i)
                a4[i] = *reinterpret_cast<const float4*>(&At[ti + i * 16][d]);
#pragma unroll
            for (int i = 0; i < 4; ++i)
                b4[i] = *reinterpret_cast<const float4*>(&Bt[tj + i * 16][d]);
#pragma unroll
            for (int qi = 0; qi < 4; ++qi)
#pragma unroll
                for (int ki = 0; ki < 4; ++ki)
                    acc[qi][ki] += a4[qi].x * b4[ki].x + a4[qi].y * b4[ki].y
                                 + a4[qi].z * b4[ki].z + a4[qi].w * b4[ki].w;
        }
    }

#pragma unroll
    for (int qi = 0; qi < 4; ++qi) {
        int m = mbase + ti + qi * 16;
        int l = m >> 2;          // m / B
        int b = m & 3;           // m % B
#pragma unroll
        for (int ki = 0; ki < 4; ++ki) {
            int n  = nbase + tj + ki * 16;
            int h  = n >> 6;
            int dk = n & 63;
            Out[(((size_t)(b * HH + h)) * LL + l) * DKK + dk] = acc[qi][ki] + bias[n];
        }
    }
}

// ---------------------------------------------------------------------------
// scorez: Z[bh,q] = sum_k exp( (Qh[bh,q]·Kh[bh,k]) / 8 )   (no max needed)
// grid: (L/64, B*H). 64x64 tiles, 4x4 micro, fp32.
// ---------------------------------------------------------------------------
__global__ __launch_bounds__(256) void scorez_kernel(
    const float* __restrict__ Qh, const float* __restrict__ Kh,
    float* __restrict__ Z)
{
    __shared__ float Qt[64][68];
    __shared__ float Kt[64][68];
    const int t  = threadIdx.x;
    const int ti = t >> 4;
    const int tj = t & 15;
    const int bh = blockIdx.y;
    const int qbase = blockIdx.x * 64;
    const float* Qp = Qh + (size_t)bh * LL * DKK;
    const float* Kp = Kh + (size_t)bh * LL * DKK;

#pragma unroll
    for (int i = 0; i < 4; ++i) {
        int flat = t + i * 256;
        int r = flat >> 4;
        int c = (flat & 15) << 2;
        *reinterpret_cast<float4*>(&Qt[r][c]) =
            *reinterpret_cast<const float4*>(&Qp[(size_t)(qbase + r) * DKK + c]);
    }

    float zacc[4] = {0.f, 0.f, 0.f, 0.f};

    for (int kt = 0; kt < LL; kt += 64) {
        __syncthreads();   // protect Kt from previous iter's readers (also covers Qt store, iter 0)
#pragma unroll
        for (int i = 0; i < 4; ++i) {
            int flat = t + i * 256;
            int r = flat >> 4;
            int c = (flat & 15) << 2;
            *reinterpret_cast<float4*>(&Kt[r][c]) =
                *reinterpret_cast<const float4*>(&Kp[(size_t)(kt + r) * DKK + c]);
        }
        __syncthreads();

        float sacc[4][4] = {};
#pragma unroll
        for (int d = 0; d < 64; d += 4) {
            float4 a4[4], b4[4];
#pragma unroll
            for (int i = 0; i < 4; ++i)
                a4[i] = *reinterpret_cast<const float4*>(&Qt[ti + i * 16][d]);
#pragma unroll
            for (int i = 0; i < 4; ++i)
                b4[i] = *reinterpret_cast<const float4*>(&Kt[tj + i * 16][d]);
#pragma unroll
            for (int qi = 0; qi < 4; ++qi)
#pragma unroll
                for (int ki = 0; ki < 4; ++ki)
                    sacc[qi][ki] += a4[qi].x * b4[ki].x + a4[qi].y * b4[ki].y
                                  + a4[qi].z * b4[ki].z + a4[qi].w * b4[ki].w;
        }
#pragma unroll
        for (int qi = 0; qi < 4; ++qi)
#pragma unroll
            for (int ki = 0; ki < 4; ++ki)
                zacc[qi] += __expf(sacc[qi][ki] * 0.125f);
    }

    __syncthreads();
    float* red = &Qt[0][0];          // reuse LDS: 64 rows x 16 partials
#pragma unroll
    for (int qi = 0; qi < 4; ++qi)
        red[(ti + qi * 16) * 16 + tj] = zacc[qi];
    __syncthreads();
    if (t < 64) {
        float z = 0.f;
#pragma unroll
        for (int j = 0; j < 16; ++j) z += red[t * 16 + j];
        Z[(size_t)bh * LL + qbase + t] = z;
    }
}

// ---------------------------------------------------------------------------
// band: per (b,q): recompute band scores, head-avg, *dist, normalize;
// write weighted band + out[q,b,:] = sum_band w * v[k,b,:]
// grid: B*L blocks of 256.
// ---------------------------------------------------------------------------
__global__ __launch_bounds__(256) void band_kernel(
    const float* __restrict__ Qh, const float* __restrict__ Kh,
    const float* __restrict__ Z, const float* __restrict__ v,
    float* __restrict__ out, float* __restrict__ wout)
{
    const int idx = blockIdx.x;
    const int b = idx & 3;
    const int q = idx >> 2;
    __shared__ float aph[HH * NBAND];
    __shared__ float att[NBAND];
    __shared__ float wgt[NBAND];
    const int t = threadIdx.x;

    if (t < HH * NBAND) {
        const int h = t / NBAND;
        const int j = t - h * NBAND;
        const int k = q - WBAND + j;
        float a = 0.f;
        if (k >= 0 && k < LL) {
            const float4* qp = reinterpret_cast<const float4*>(
                &Qh[(((size_t)b * HH + h) * LL + q) * DKK]);
            const float4* kp = reinterpret_cast<const float4*>(
                &Kh[(((size_t)b * HH + h) * LL + k) * DKK]);
            float s = 0.f;
#pragma unroll
            for (int i = 0; i < 16; ++i) {
                float4 qa = qp[i], ka = kp[i];
                s += qa.x * ka.x + qa.y * ka.y + qa.z * ka.z + qa.w * ka.w;
            }
            a = __expf(s * 0.125f) / Z[((size_t)b * HH + h) * LL + q];
        }
        aph[t] = a;
    }
    __syncthreads();

    if (t < NBAND) {
        float s = 0.f;
#pragma unroll
        for (int h = 0; h < HH; ++h) s += aph[h * NBAND + t];
        float dd = (float)(t - WBAND);
        att[t] = s * __expf(-0.5f * dd * dd);
    }
    __syncthreads();

    if (t < NBAND) {
        float wsum = 0.f;
#pragma unroll
        for (int j = 0; j < NBAND; ++j) wsum += att[j];
        float wv = att[t] / wsum;
        wgt[t] = wv;
        int k = q - WBAND + t;
        if (k >= 0 && k < LL) wout[((size_t)b * LL + q) * LL + k] = wv;
    }
    __syncthreads();

    for (int d = t; d < DD; d += 256) {
        float acc = 0.f;
#pragma unroll
        for (int j = 0; j < NBAND; ++j) {
            int k  = q - WBAND + j;
            int kc = k < 0 ? 0 : (k >= LL ? LL - 1 : k);   // wgt[j]==0 when clipped
            acc += wgt[j] * v[((size_t)kc * BB + b) * DD + d];
        }
        out[((size_t)q * BB + b) * DD + d] = acc;
    }
}

// ---------------------------------------------------------------------------
extern "C" void kernel_launch(void* const* d_in, const int* in_sizes, int n_in,
                              void* d_out, int out_size, void* d_ws, size_t ws_size,
                              hipStream_t stream) {
    const float* q  = (const float*)d_in[0];
    const float* k  = (const float*)d_in[1];
    const float* v  = (const float*)d_in[2];
    const float* Wq = (const float*)d_in[3];
    const float* bq = (const float*)d_in[4];
    const float* Wk = (const float*)d_in[5];
    const float* bk = (const float*)d_in[6];

    float* out  = (float*)d_out;                       // [L,B,D]
    float* wout = out + (size_t)LL * BB * DD;          // [B,L,L]

    float* Qh = (float*)d_ws;                          // [B,H,L,DK] 16 MB
    float* Kh = Qh + (size_t)BB * HH * LL * DKK;       // [B,H,L,DK] 16 MB
    float* Z  = Kh + (size_t)BB * HH * LL * DKK;       // [B*H*L]   256 KB

    // zero the dense weighted output (band entries overwritten below)
    hipMemsetAsync(wout, 0, (size_t)BB * LL * LL * sizeof(float), stream);

    dim3 gp(LL * BB / 64, DD / 64);                    // 128 x 8
    proj_kernel<<<gp, 256, 0, stream>>>(q, Wq, bq, Qh);
    proj_kernel<<<gp, 256, 0, stream>>>(k, Wk, bk, Kh);

    scorez_kernel<<<dim3(LL / 64, BB * HH), 256, 0, stream>>>(Qh, Kh, Z);

    band_kernel<<<BB * LL, 256, 0, stream>>>(Qh, Kh, Z, v, out, wout);
}

// Round 2
// 165.628 us; speedup vs baseline: 3.8251x; 3.8251x over previous
//
#include <hip/hip_runtime.h>

#define LL   2048
#define BB   4
#define DD   512
#define HH   8
#define DKK  64
#define WBAND 12
#define NBAND 25   // 2*WBAND+1

typedef __attribute__((ext_vector_type(8))) short  bf16x8;
typedef __attribute__((ext_vector_type(4))) float  f32x4;

static __device__ __forceinline__ float bf2f(unsigned short u) {
    union { unsigned int i; float f; } c; c.i = ((unsigned int)u) << 16; return c.f;
}
static __device__ __forceinline__ unsigned short f2bf(float f) {
    union { float f; unsigned int i; } c; c.f = f;
    unsigned int x = c.i;
    return (unsigned short)((x + 0x7fffu + ((x >> 16) & 1u)) >> 16);  // RNE
}
static __device__ __forceinline__ bf16x8 pack8(float4 x0, float4 x1) {
    bf16x8 r;
    r[0] = (short)f2bf(x0.x); r[1] = (short)f2bf(x0.y);
    r[2] = (short)f2bf(x0.z); r[3] = (short)f2bf(x0.w);
    r[4] = (short)f2bf(x1.x); r[5] = (short)f2bf(x1.y);
    r[6] = (short)f2bf(x1.z); r[7] = (short)f2bf(x1.w);
    return r;
}

// ---------------------------------------------------------------------------
// proj: Out[b,h,l,dk] = ((X @ Wm^T)[m,n] + bias[n]) * scale, stored bf16.
// M=L*B=8192, N=512, K=512. Block = 128x128 tile, 4 waves (each 64x64).
// Direct global->reg->bf16 cvt->MFMA (no LDS). A/B frag: row=lane&15,
// k = 8*(lane>>4)+j (+32 per kstep).  C/D: col=lane&15, row=(lane>>4)*4+reg.
// ---------------------------------------------------------------------------
__global__ __launch_bounds__(256) void proj_mfma(
    const float* __restrict__ X, const float* __restrict__ Wm,
    const float* __restrict__ bias, unsigned short* __restrict__ Out,
    float scale)
{
    const int t  = threadIdx.x;
    const int w  = t >> 6;
    const int l  = t & 63;
    const int mb = blockIdx.x * 128 + (w >> 1) * 64;
    const int nb = blockIdx.y * 128 + (w & 1) * 64;
    const int lr = l & 15;
    const int lk = (l >> 4) * 8;

    f32x4 acc[4][4] = {};

    for (int ks = 0; ks < DD; ks += 32) {
        bf16x8 a[4], b[4];
#pragma unroll
        for (int mi = 0; mi < 4; ++mi) {
            const float* p = &X[(size_t)(mb + 16 * mi + lr) * DD + ks + lk];
            a[mi] = pack8(*(const float4*)p, *(const float4*)(p + 4));
        }
#pragma unroll
        for (int ni = 0; ni < 4; ++ni) {
            const float* p = &Wm[(size_t)(nb + 16 * ni + lr) * DD + ks + lk];
            b[ni] = pack8(*(const float4*)p, *(const float4*)(p + 4));
        }
#pragma unroll
        for (int mi = 0; mi < 4; ++mi)
#pragma unroll
            for (int ni = 0; ni < 4; ++ni)
                acc[mi][ni] = __builtin_amdgcn_mfma_f32_16x16x32_bf16(
                    a[mi], b[ni], acc[mi][ni], 0, 0, 0);
    }

#pragma unroll
    for (int mi = 0; mi < 4; ++mi)
#pragma unroll
        for (int j = 0; j < 4; ++j) {
            const int m    = mb + 16 * mi + (l >> 4) * 4 + j;
            const int lseq = m >> 2;
            const int bidx = m & 3;
#pragma unroll
            for (int ni = 0; ni < 4; ++ni) {
                const int n  = nb + 16 * ni + lr;
                const int h  = n >> 6;
                const int dk = n & 63;
                const float val = (acc[mi][ni][j] + bias[n]) * scale;
                Out[(((size_t)(bidx * HH + h)) * LL + lseq) * DKK + dk] = f2bf(val);
            }
        }
}

// ---------------------------------------------------------------------------
// scorez: Z[bh,q] = sum_k exp( Qh[bh,q] . Kh[bh,k] )   (Q pre-scaled by 1/8)
// grid: (L/64, B*H); block 256 = 4 waves. Each wave: all 64 q-rows (A-frags
// resident in regs), k-quarter of 512 streamed from global. No LDS staging.
// ---------------------------------------------------------------------------
__global__ __launch_bounds__(256) void scorez_mfma(
    const unsigned short* __restrict__ Qh, const unsigned short* __restrict__ Kh,
    float* __restrict__ Z)
{
    __shared__ float Zp[4][64];
    const int t  = threadIdx.x;
    const int w  = t >> 6;
    const int l  = t & 63;
    const int bh = blockIdx.y;
    const int qb = blockIdx.x * 64;
    const int lr = l & 15;
    const int lk = (l >> 4) * 8;
    const unsigned short* Qp = Qh + (size_t)bh * LL * DKK;
    const unsigned short* Kp = Kh + (size_t)bh * LL * DKK;

    bf16x8 qa[4][2];
#pragma unroll
    for (int r = 0; r < 4; ++r)
#pragma unroll
        for (int s = 0; s < 2; ++s)
            qa[r][s] = *(const bf16x8*)&Qp[(size_t)(qb + 16 * r + lr) * DKK + 32 * s + lk];

    float zacc[4][4] = {};
    const int k0 = w * 512;
    for (int kt = k0; kt < k0 + 512; kt += 16) {
        const bf16x8 kb0 = *(const bf16x8*)&Kp[(size_t)(kt + lr) * DKK + lk];
        const bf16x8 kb1 = *(const bf16x8*)&Kp[(size_t)(kt + lr) * DKK + 32 + lk];
#pragma unroll
        for (int r = 0; r < 4; ++r) {
            f32x4 acc = {0.f, 0.f, 0.f, 0.f};
            acc = __builtin_amdgcn_mfma_f32_16x16x32_bf16(qa[r][0], kb0, acc, 0, 0, 0);
            acc = __builtin_amdgcn_mfma_f32_16x16x32_bf16(qa[r][1], kb1, acc, 0, 0, 0);
#pragma unroll
            for (int j = 0; j < 4; ++j)
                zacc[r][j] += __expf(acc[j]);
        }
    }

    // reduce across the 16 lanes (k-columns) of each lane-group
#pragma unroll
    for (int m = 8; m >= 1; m >>= 1)
#pragma unroll
        for (int r = 0; r < 4; ++r)
#pragma unroll
            for (int j = 0; j < 4; ++j)
                zacc[r][j] += __shfl_xor(zacc[r][j], m, 64);

    if (lr == 0) {
#pragma unroll
        for (int r = 0; r < 4; ++r)
#pragma unroll
            for (int j = 0; j < 4; ++j)
                Zp[w][16 * r + (l >> 4) * 4 + j] = zacc[r][j];
    }
    __syncthreads();
    if (t < 64)
        Z[(size_t)bh * LL + qb + t] = Zp[0][t] + Zp[1][t] + Zp[2][t] + Zp[3][t];
}

// ---------------------------------------------------------------------------
// band: per (b,q): recompute band scores (bf16), head-avg, *dist, normalize;
// write the FULL weighted row (zeros outside band — replaces memset) and
// out[q,b,:] = sum_band w * v[k,b,:].
// ---------------------------------------------------------------------------
__global__ __launch_bounds__(256) void band_kernel(
    const unsigned short* __restrict__ Qh, const unsigned short* __restrict__ Kh,
    const float* __restrict__ Z, const float* __restrict__ v,
    float* __restrict__ out, float* __restrict__ wout)
{
    const int idx = blockIdx.x;
    const int b = idx & 3;
    const int q = idx >> 2;
    __shared__ float aph[HH * NBAND];
    __shared__ float att[NBAND];
    __shared__ float wgt[NBAND];
    const int t = threadIdx.x;

    if (t < HH * NBAND) {
        const int h = t / NBAND;
        const int j = t - h * NBAND;
        const int k = q - WBAND + j;
        float a = 0.f;
        if (k >= 0 && k < LL) {
            const bf16x8* qp = (const bf16x8*)&Qh[(((size_t)b * HH + h) * LL + q) * DKK];
            const bf16x8* kp = (const bf16x8*)&Kh[(((size_t)b * HH + h) * LL + k) * DKK];
            float s = 0.f;
#pragma unroll
            for (int i = 0; i < 8; ++i) {
                const bf16x8 qa = qp[i], ka = kp[i];
#pragma unroll
                for (int e = 0; e < 8; ++e)
                    s += bf2f((unsigned short)qa[e]) * bf2f((unsigned short)ka[e]);
            }
            a = __expf(s) / Z[((size_t)b * HH + h) * LL + q];
        }
        aph[t] = a;
    }
    __syncthreads();

    if (t < NBAND) {
        float s = 0.f;
#pragma unroll
        for (int h = 0; h < HH; ++h) s += aph[h * NBAND + t];
        const float dd = (float)(t - WBAND);
        att[t] = s * __expf(-0.5f * dd * dd);
    }
    __syncthreads();

    if (t < NBAND) {
        float wsum = 0.f;
#pragma unroll
        for (int j = 0; j < NBAND; ++j) wsum += att[j];
        wgt[t] = att[t] / wsum;
    }
    __syncthreads();

    // full weighted row (band values, zeros elsewhere)
    float* wrow = &wout[((size_t)b * LL + q) * LL];
    for (int c4 = t; c4 < LL / 4; c4 += 256) {
        const int c = c4 * 4;
        float4 vw;
        float* pv = reinterpret_cast<float*>(&vw);
#pragma unroll
        for (int e = 0; e < 4; ++e) {
            const int d = (c + e) - q + WBAND;
            pv[e] = (d >= 0 && d < NBAND) ? wgt[d] : 0.f;
        }
        *(float4*)&wrow[c] = vw;
    }

    // out[q,b,:] — 128 lanes x float4
    if (t < 128) {
        const int d = t * 4;
        float4 accv = {0.f, 0.f, 0.f, 0.f};
#pragma unroll
        for (int j = 0; j < NBAND; ++j) {
            const int k = q - WBAND + j;
            if (k < 0 || k >= LL) continue;   // wgt[j] == 0 there
            const float wv = wgt[j];
            const float4 vv = *(const float4*)&v[((size_t)k * BB + b) * DD + d];
            accv.x += wv * vv.x; accv.y += wv * vv.y;
            accv.z += wv * vv.z; accv.w += wv * vv.w;
        }
        *(float4*)&out[((size_t)q * BB + b) * DD + d] = accv;
    }
}

// ---------------------------------------------------------------------------
extern "C" void kernel_launch(void* const* d_in, const int* in_sizes, int n_in,
                              void* d_out, int out_size, void* d_ws, size_t ws_size,
                              hipStream_t stream) {
    const float* q  = (const float*)d_in[0];
    const float* k  = (const float*)d_in[1];
    const float* v  = (const float*)d_in[2];
    const float* Wq = (const float*)d_in[3];
    const float* bq = (const float*)d_in[4];
    const float* Wk = (const float*)d_in[5];
    const float* bk = (const float*)d_in[6];

    float* out  = (float*)d_out;                       // [L,B,D]
    float* wout = out + (size_t)LL * BB * DD;          // [B,L,L]

    unsigned short* Qh = (unsigned short*)d_ws;                 // [B,H,L,DK] bf16, 8 MB
    unsigned short* Kh = Qh + (size_t)BB * HH * LL * DKK;       // [B,H,L,DK] bf16, 8 MB
    float* Z = (float*)(Kh + (size_t)BB * HH * LL * DKK);       // [B*H*L] 256 KB

    dim3 gp(LL * BB / 128, DD / 128);                  // 64 x 4
    proj_mfma<<<gp, 256, 0, stream>>>(q, Wq, bq, Qh, 0.125f);  // Q pre-scaled 1/8
    proj_mfma<<<gp, 256, 0, stream>>>(k, Wk, bk, Kh, 1.0f);

    scorez_mfma<<<dim3(LL / 64, BB * HH), 256, 0, stream>>>(Qh, Kh, Z);

    band_kernel<<<BB * LL, 256, 0, stream>>>(Qh, Kh, Z, v, out, wout);
}